// Round 5
// baseline (2247.958 us; speedup 1.0000x reference)
//
#include <hip/hip_runtime.h>
#include <math.h>
#include <stdint.h>

#define N_NODES 50000
#define N_EDGES 400000
#define N_T 4
#define N_R 8
#define N_H 8
#define DKD 32
#define D 256
#define TM 64
#define N_SEG (N_NODES * N_R)
#define PROJ_BLOCKS ((N_NODES + TM - 1) / TM + N_T)   // 786 >= sum of per-type ceils

typedef _Float16 h2 __attribute__((ext_vector_type(2)));
typedef _Float16 v8h __attribute__((ext_vector_type(8)));
typedef float v4f __attribute__((ext_vector_type(4)));
typedef unsigned short u16;

__device__ __forceinline__ u16 h2u(_Float16 h) { return __builtin_bit_cast(u16, h); }
__device__ __forceinline__ h2 u2h2(unsigned int u) { return __builtin_bit_cast(h2, u); }

// dot2 of f16 pairs with f32 accumulate: v_dot2_f32_f16 (1 instr = 2 MAC, no unpack)
#if __has_builtin(__builtin_amdgcn_fdot2)
__device__ __forceinline__ float fdot2f(h2 a, h2 b, float c) {
    return __builtin_amdgcn_fdot2(a, b, c, false);
}
#else
__device__ __forceinline__ float fdot2f(h2 a, h2 b, float c) {
    return c + (float)a[0] * (float)b[0] + (float)a[1] * (float)b[1];
}
#endif

__device__ __forceinline__ unsigned int pk16(float a, float b) {
#if __has_builtin(__builtin_amdgcn_cvt_pkrtz)
    return __builtin_bit_cast(unsigned int, __builtin_amdgcn_cvt_pkrtz(a, b));
#else
    return __builtin_bit_cast(unsigned int, h2{(_Float16)a, (_Float16)b});
#endif
}

struct Q4 { uint4 a, b, c, d; };

// 32-elem f16 dot: 64B row (4 uint4) . register operand — 16 fdot2, all static
__device__ __forceinline__ float dot32q(const uint4* __restrict__ m, const Q4& q) {
    uint4 m0 = m[0], m1 = m[1], m2 = m[2], m3 = m[3];
    float s = 0.f;
    s = fdot2f(u2h2(m0.x), u2h2(q.a.x), s);
    s = fdot2f(u2h2(m0.y), u2h2(q.a.y), s);
    s = fdot2f(u2h2(m0.z), u2h2(q.a.z), s);
    s = fdot2f(u2h2(m0.w), u2h2(q.a.w), s);
    s = fdot2f(u2h2(m1.x), u2h2(q.b.x), s);
    s = fdot2f(u2h2(m1.y), u2h2(q.b.y), s);
    s = fdot2f(u2h2(m1.z), u2h2(q.b.z), s);
    s = fdot2f(u2h2(m1.w), u2h2(q.b.w), s);
    s = fdot2f(u2h2(m2.x), u2h2(q.c.x), s);
    s = fdot2f(u2h2(m2.y), u2h2(q.c.y), s);
    s = fdot2f(u2h2(m2.z), u2h2(q.c.z), s);
    s = fdot2f(u2h2(m2.w), u2h2(q.c.w), s);
    s = fdot2f(u2h2(m3.x), u2h2(q.d.x), s);
    s = fdot2f(u2h2(m3.y), u2h2(q.d.y), s);
    s = fdot2f(u2h2(m3.z), u2h2(q.d.z), s);
    s = fdot2f(u2h2(m3.w), u2h2(q.d.w), s);
    return s;
}

// ---------------- f32 -> f16 weight conversions ----------------
__global__ __launch_bounds__(256) void k_cvtW(
    const float4* __restrict__ w0, const float4* __restrict__ w1,
    const float4* __restrict__ w2, const float4* __restrict__ w3,
    ushort4* __restrict__ d, int n4each) {
    int i = blockIdx.x * 256 + threadIdx.x;
    if (i >= 4 * n4each) return;
    int sel = i / n4each, j = i - sel * n4each;
    const float4* s = (sel == 0) ? w0 : (sel == 1) ? w1 : (sel == 2) ? w2 : w3;
    float4 v = s[j];
    ushort4 o;
    o.x = h2u((_Float16)v.x); o.y = h2u((_Float16)v.y);
    o.z = h2u((_Float16)v.z); o.w = h2u((_Float16)v.w);
    d[i] = o;
}

// rel_att scaled by pri[r][h]/sqrt(dk)*log2(e) folded in (softmax via exp2)
__global__ __launch_bounds__(256) void k_cvt_att(const float4* __restrict__ s,
                                                 const float* __restrict__ pri,
                                                 ushort4* __restrict__ d, int n4) {
    int i = blockIdx.x * 256 + threadIdx.x;
    if (i >= n4) return;
    int mat = i >> 8;                         // 1024 elems = 256 float4 per matrix
    float sc = pri[mat] * 0.2550309305920868f;   // (1/sqrt(32)) * log2(e)
    float4 v = s[i];
    ushort4 o;
    o.x = h2u((_Float16)(v.x * sc)); o.y = h2u((_Float16)(v.y * sc));
    o.z = h2u((_Float16)(v.z * sc)); o.w = h2u((_Float16)(v.w * sc));
    d[i] = o;
}

// rel_msg [mat][d0][f] f32 -> Mt [mat][f][d0] f16 (per 32x32 matrix transpose)
__global__ __launch_bounds__(256) void k_cvt_t(const float* __restrict__ s,
                                               u16* __restrict__ d) {
    int i = blockIdx.x * 256 + threadIdx.x;
    if (i >= N_R * N_H * DKD * DKD) return;
    int mat = i >> 10, w = i & 1023;
    int d0 = w >> 5, f = w & 31;
    d[(mat << 10) + f * DKD + d0] = h2u((_Float16)s[i]);
}

// ---------------- bucketing by node type ----------------
__global__ void k_hist(const int* __restrict__ nt, int* __restrict__ cnt) {
    int n = blockIdx.x * blockDim.x + threadIdx.x;
    if (n < N_NODES) atomicAdd(&cnt[nt[n]], 1);
}

__global__ void k_scan(const int* __restrict__ cnt, int* __restrict__ off,
                       int* __restrict__ toff) {
    int o = 0, to = 0;
    for (int t = 0; t < N_T; t++) {
        off[t] = o; toff[t] = to;
        o += cnt[t]; to += (cnt[t] + TM - 1) / TM;
    }
    off[N_T] = o; toff[N_T] = to;
}

__global__ void k_scatter(const int* __restrict__ nt, const int* __restrict__ off,
                          int* __restrict__ cur, int* __restrict__ order) {
    int n = blockIdx.x * blockDim.x + threadIdx.x;
    if (n >= N_NODES) return;
    int t = nt[n];
    int pos = off[t] + atomicAdd(&cur[t], 1);
    order[pos] = n;
}

// ---------------- segment CSR (seg = dst*R + etype) ----------------
__global__ void k_hist_seg(const int* __restrict__ dst, const int* __restrict__ et,
                           int* __restrict__ cnt) {
    int e = blockIdx.x * blockDim.x + threadIdx.x;
    if (e < N_EDGES) atomicAdd(&cnt[dst[e] * N_R + et[e]], 1);
}

// level 1: per-block (1024) exclusive scan + block sums
__global__ __launch_bounds__(1024) void k_scan_l1(const int* __restrict__ cnt,
                                                  int* __restrict__ excl,
                                                  int* __restrict__ bsum) {
    __shared__ int sh[1024];
    int tid = threadIdx.x, i = blockIdx.x * 1024 + tid;
    int v = (i < N_SEG) ? cnt[i] : 0;
    sh[tid] = v;
    __syncthreads();
    #pragma unroll
    for (int ofs = 1; ofs < 1024; ofs <<= 1) {
        int t = (tid >= ofs) ? sh[tid - ofs] : 0;
        __syncthreads();
        sh[tid] += t;
        __syncthreads();
    }
    if (i < N_SEG) excl[i] = sh[tid] - v;
    if (tid == 1023) bsum[blockIdx.x] = sh[1023];
}

// level 2: single block exclusive scan of block sums (NB <= 512)
__global__ __launch_bounds__(512) void k_scan_l2(int* __restrict__ bsum, int NB) {
    __shared__ int sh[512];
    int tid = threadIdx.x;
    int v = (tid < NB) ? bsum[tid] : 0;
    sh[tid] = v;
    __syncthreads();
    #pragma unroll
    for (int ofs = 1; ofs < 512; ofs <<= 1) {
        int t = (tid >= ofs) ? sh[tid - ofs] : 0;
        __syncthreads();
        sh[tid] += t;
        __syncthreads();
    }
    if (tid < NB) bsum[tid] = sh[tid] - v;
}

// level 3: add block offsets, set final rowptr entry
__global__ void k_scan_l3(int* __restrict__ excl, const int* __restrict__ bsum) {
    int i = blockIdx.x * blockDim.x + threadIdx.x;
    if (i < N_SEG) excl[i] += bsum[i >> 10];
    else if (i == N_SEG) excl[N_SEG] = N_EDGES;
}

// scatter src node id per segment slot
__global__ void k_scatter_seg(const int* __restrict__ src, const int* __restrict__ dst,
                              const int* __restrict__ et, const int* __restrict__ rp,
                              int* __restrict__ cur, int* __restrict__ esrc) {
    int e = blockIdx.x * blockDim.x + threadIdx.x;
    if (e >= N_EDGES) return;
    int sg = dst[e] * N_R + et[e];
    int pos = rp[sg] + atomicAdd(&cur[sg], 1);
    esrc[pos] = src[e];
}

// ---------------- fused typed K/Q/V projection (MFMA, f16) ----------------
__global__ __launch_bounds__(256) void k_proj(
    const float* __restrict__ x, const int* __restrict__ order,
    const int* __restrict__ off, const int* __restrict__ toff,
    const u16* __restrict__ Wkb, const float* __restrict__ bk,
    const u16* __restrict__ Wqb, const float* __restrict__ bq,
    const u16* __restrict__ Wvb, const float* __restrict__ bv,
    u16* __restrict__ Kb, u16* __restrict__ Qb, u16* __restrict__ Vb) {
    __shared__ __align__(16) u16 xs[TM][D + 8];
    int b = blockIdx.x;
    int t = -1;
    #pragma unroll
    for (int i = 0; i < N_T; i++)
        if (b >= toff[i] && b < toff[i + 1]) t = i;
    if (t < 0) return;
    int nodeBase = off[t] + (b - toff[t]) * TM;
    int count = min(TM, off[t + 1] - nodeBase);
    int tid = threadIdx.x;

    for (int j = tid; j < TM * (D / 4); j += 256) {
        int row = j >> 6, ch = j & 63;
        float4 v = {0.f, 0.f, 0.f, 0.f};
        if (row < count) {
            int g = order[nodeBase + row];
            v = *(const float4*)(x + (size_t)g * D + ch * 4);
        }
        ushort4 o;
        o.x = h2u((_Float16)v.x); o.y = h2u((_Float16)v.y);
        o.z = h2u((_Float16)v.z); o.w = h2u((_Float16)v.w);
        *(ushort4*)&xs[row][ch * 4] = o;
    }
    __syncthreads();

    int lane = tid & 63, wave = tid >> 6;
    int m = lane & 15, quad = lane >> 4;
    v8h a[8];
    #pragma unroll
    for (int ks = 0; ks < 8; ks++)
        a[ks] = *(const v8h*)&xs[wave * 16 + m][ks * 32 + quad * 8];

    int grow[4]; bool vrow[4];
    #pragma unroll
    for (int r = 0; r < 4; r++) {
        int rowi = wave * 16 + quad * 4 + r;
        vrow[r] = (rowi < count);
        grow[r] = vrow[r] ? order[nodeBase + rowi] : 0;
    }

    const u16* Ws[3] = {Wkb + (size_t)t * D * D, Wqb + (size_t)t * D * D, Wvb + (size_t)t * D * D};
    const float* Bs[3] = {bk + t * D, bq + t * D, bv + t * D};
    u16* Os[3] = {Kb, Qb, Vb};

    for (int p = 0; p < 3; p++) {
        const u16* W = Ws[p];
        for (int dt = 0; dt < 16; dt++) {
            int dcol = dt * 16 + m;
            v4f acc = {0.f, 0.f, 0.f, 0.f};
            #pragma unroll
            for (int ks = 0; ks < 8; ks++) {
                v8h bf = *(const v8h*)(W + (size_t)dcol * D + ks * 32 + quad * 8);
                acc = __builtin_amdgcn_mfma_f32_16x16x32_f16(a[ks], bf, acc, 0, 0, 0);
            }
            float bias = Bs[p][dcol];
            #pragma unroll
            for (int r = 0; r < 4; r++) {
                if (vrow[r])
                    Os[p][(size_t)grow[r] * D + dcol] = h2u((_Float16)(acc[r] + bias));
            }
        }
    }
}

// ---------------- fused attention + softmax + aggregation + msg transform ----
// ONE LANE PER (node, head): lanes 8g..8g+7 own node g's heads. Each lane:
//   for each present r (CSR order):
//     qtilde = A_r_h @ q   (32x 16-fdot2 rows, in-register)
//     for e in seg: p = k_src . qtilde (16 fdot2, NO shfl); ex = exp2(p)
//                   den += ex; U[32] += ex * v_src
//     macc[32] += M_r_h @ (U/den)
//   out = macc/np -> own 64B slice of TBF (aliases Qb; read-own/write-own).
// No shfl, no switches, no LDS, no wave barriers — pure per-lane dataflow.
__global__ __launch_bounds__(256) void k_fused(
    const u16* __restrict__ Kb, u16* QTb, const u16* __restrict__ Vb,
    const int* __restrict__ rowptr, const int* __restrict__ esrc,
    const u16* __restrict__ Ab, const u16* __restrict__ Mtb) {
    int tid = threadIdx.x;
    int n = blockIdx.x * 32 + (tid >> 3);
    if (n >= N_NODES) return;
    int h = tid & 7;
    int base = n * N_R;
    u16* qrow = QTb + (size_t)n * D + h * DKD;     // own 32-f16 slice

    float macc[DKD];
    #pragma unroll
    for (int j = 0; j < DKD; j++) macc[j] = 0.f;
    float np = 0.f;

    int s0 = rowptr[base];
    for (int r = 0; r < N_R; r++) {
        int s1 = rowptr[base + r + 1];
        if (s0 < s1) {
            np += 1.f;
            // ---- load own q (hot in L1 after first r) ----
            Q4 q4;
            {
                const uint4* qp = (const uint4*)qrow;
                q4.a = qp[0]; q4.b = qp[1]; q4.c = qp[2]; q4.d = qp[3];
            }
            // ---- qtilde = A_scaled @ q : 32 rows ----
            const uint4* Ar = (const uint4*)(Ab + ((size_t)(r * N_H + h) << 10));
            Q4 qt;
            {
                float t0, t1;
                t0 = dot32q(Ar + 0, q4);  t1 = dot32q(Ar + 4, q4);  qt.a.x = pk16(t0, t1);
                t0 = dot32q(Ar + 8, q4);  t1 = dot32q(Ar + 12, q4); qt.a.y = pk16(t0, t1);
                t0 = dot32q(Ar + 16, q4); t1 = dot32q(Ar + 20, q4); qt.a.z = pk16(t0, t1);
                t0 = dot32q(Ar + 24, q4); t1 = dot32q(Ar + 28, q4); qt.a.w = pk16(t0, t1);
                t0 = dot32q(Ar + 32, q4); t1 = dot32q(Ar + 36, q4); qt.b.x = pk16(t0, t1);
                t0 = dot32q(Ar + 40, q4); t1 = dot32q(Ar + 44, q4); qt.b.y = pk16(t0, t1);
                t0 = dot32q(Ar + 48, q4); t1 = dot32q(Ar + 52, q4); qt.b.z = pk16(t0, t1);
                t0 = dot32q(Ar + 56, q4); t1 = dot32q(Ar + 60, q4); qt.b.w = pk16(t0, t1);
                t0 = dot32q(Ar + 64, q4); t1 = dot32q(Ar + 68, q4); qt.c.x = pk16(t0, t1);
                t0 = dot32q(Ar + 72, q4); t1 = dot32q(Ar + 76, q4); qt.c.y = pk16(t0, t1);
                t0 = dot32q(Ar + 80, q4); t1 = dot32q(Ar + 84, q4); qt.c.z = pk16(t0, t1);
                t0 = dot32q(Ar + 88, q4); t1 = dot32q(Ar + 92, q4); qt.c.w = pk16(t0, t1);
                t0 = dot32q(Ar + 96, q4); t1 = dot32q(Ar + 100, q4); qt.d.x = pk16(t0, t1);
                t0 = dot32q(Ar + 104, q4); t1 = dot32q(Ar + 108, q4); qt.d.y = pk16(t0, t1);
                t0 = dot32q(Ar + 112, q4); t1 = dot32q(Ar + 116, q4); qt.d.z = pk16(t0, t1);
                t0 = dot32q(Ar + 120, q4); t1 = dot32q(Ar + 124, q4); qt.d.w = pk16(t0, t1);
            }
            // ---- edge loop over this segment ----
            float den = 0.f;
            float U[DKD];
            #pragma unroll
            for (int j = 0; j < DKD; j++) U[j] = 0.f;
            for (int e = s0; e < s1; e++) {
                int s = esrc[e];                           // shared by 8 h-lanes
                const uint4* kp = (const uint4*)(Kb + (size_t)s * D + h * DKD);
                const uint4* vp = (const uint4*)(Vb + (size_t)s * D + h * DKD);
                Q4 kv; kv.a = kp[0]; kv.b = kp[1]; kv.c = kp[2]; kv.d = kp[3];
                uint4 v0 = vp[0], v1 = vp[1], v2 = vp[2], v3 = vp[3];
                float p = 0.f;
                p = fdot2f(u2h2(kv.a.x), u2h2(qt.a.x), p);
                p = fdot2f(u2h2(kv.a.y), u2h2(qt.a.y), p);
                p = fdot2f(u2h2(kv.a.z), u2h2(qt.a.z), p);
                p = fdot2f(u2h2(kv.a.w), u2h2(qt.a.w), p);
                p = fdot2f(u2h2(kv.b.x), u2h2(qt.b.x), p);
                p = fdot2f(u2h2(kv.b.y), u2h2(qt.b.y), p);
                p = fdot2f(u2h2(kv.b.z), u2h2(qt.b.z), p);
                p = fdot2f(u2h2(kv.b.w), u2h2(qt.b.w), p);
                p = fdot2f(u2h2(kv.c.x), u2h2(qt.c.x), p);
                p = fdot2f(u2h2(kv.c.y), u2h2(qt.c.y), p);
                p = fdot2f(u2h2(kv.c.z), u2h2(qt.c.z), p);
                p = fdot2f(u2h2(kv.c.w), u2h2(qt.c.w), p);
                p = fdot2f(u2h2(kv.d.x), u2h2(qt.d.x), p);
                p = fdot2f(u2h2(kv.d.y), u2h2(qt.d.y), p);
                p = fdot2f(u2h2(kv.d.z), u2h2(qt.d.z), p);
                p = fdot2f(u2h2(kv.d.w), u2h2(qt.d.w), p);
                float ex = exp2f(p);                       // log2e folded into A
                den += ex;
#define UACC(VV, J0) { h2 _t = u2h2(VV); U[J0] += ex * (float)_t[0]; U[J0 + 1] += ex * (float)_t[1]; }
                UACC(v0.x, 0)  UACC(v0.y, 2)  UACC(v0.z, 4)  UACC(v0.w, 6)
                UACC(v1.x, 8)  UACC(v1.y, 10) UACC(v1.z, 12) UACC(v1.w, 14)
                UACC(v2.x, 16) UACC(v2.y, 18) UACC(v2.z, 20) UACC(v2.w, 22)
                UACC(v3.x, 24) UACC(v3.y, 26) UACC(v3.z, 28) UACC(v3.w, 30)
#undef UACC
            }
            // ---- normalize, pack, M-transform ----
            float invd = 1.f / den;
            Q4 uh;
            uh.a.x = pk16(U[0] * invd, U[1] * invd);
            uh.a.y = pk16(U[2] * invd, U[3] * invd);
            uh.a.z = pk16(U[4] * invd, U[5] * invd);
            uh.a.w = pk16(U[6] * invd, U[7] * invd);
            uh.b.x = pk16(U[8] * invd, U[9] * invd);
            uh.b.y = pk16(U[10] * invd, U[11] * invd);
            uh.b.z = pk16(U[12] * invd, U[13] * invd);
            uh.b.w = pk16(U[14] * invd, U[15] * invd);
            uh.c.x = pk16(U[16] * invd, U[17] * invd);
            uh.c.y = pk16(U[18] * invd, U[19] * invd);
            uh.c.z = pk16(U[20] * invd, U[21] * invd);
            uh.c.w = pk16(U[22] * invd, U[23] * invd);
            uh.d.x = pk16(U[24] * invd, U[25] * invd);
            uh.d.y = pk16(U[26] * invd, U[27] * invd);
            uh.d.z = pk16(U[28] * invd, U[29] * invd);
            uh.d.w = pk16(U[30] * invd, U[31] * invd);
            const uint4* Mr = (const uint4*)(Mtb + ((size_t)(r * N_H + h) << 10));
            #pragma unroll
            for (int f = 0; f < DKD; f++)
                macc[f] += dot32q(Mr + f * 4, uh);
        }
        s0 = s1;
    }

    float invp = (np > 0.f) ? 1.f / np : 1.f;
    uint4 o0, o1, o2, o3;
    o0.x = pk16(macc[0] * invp, macc[1] * invp);
    o0.y = pk16(macc[2] * invp, macc[3] * invp);
    o0.z = pk16(macc[4] * invp, macc[5] * invp);
    o0.w = pk16(macc[6] * invp, macc[7] * invp);
    o1.x = pk16(macc[8] * invp, macc[9] * invp);
    o1.y = pk16(macc[10] * invp, macc[11] * invp);
    o1.z = pk16(macc[12] * invp, macc[13] * invp);
    o1.w = pk16(macc[14] * invp, macc[15] * invp);
    o2.x = pk16(macc[16] * invp, macc[17] * invp);
    o2.y = pk16(macc[18] * invp, macc[19] * invp);
    o2.z = pk16(macc[20] * invp, macc[21] * invp);
    o2.w = pk16(macc[22] * invp, macc[23] * invp);
    o3.x = pk16(macc[24] * invp, macc[25] * invp);
    o3.y = pk16(macc[26] * invp, macc[27] * invp);
    o3.z = pk16(macc[28] * invp, macc[29] * invp);
    o3.w = pk16(macc[30] * invp, macc[31] * invp);
    uint4* op = (uint4*)qrow;
    op[0] = o0; op[1] = o1; op[2] = o2; op[3] = o3;
}

// ---------------- typed output linear + sigmoid-skip blend (MFMA, f16) ----------------
__global__ __launch_bounds__(256) void k_out(
    const u16* __restrict__ TBF, const float* __restrict__ x,
    const int* __restrict__ order, const int* __restrict__ off, const int* __restrict__ toff,
    const u16* __restrict__ Wab, const float* __restrict__ ba,
    const float* __restrict__ skip, float* __restrict__ out) {
    __shared__ __align__(16) u16 xs[TM][D + 8];
    int b = blockIdx.x;
    int t = -1;
    #pragma unroll
    for (int i = 0; i < N_T; i++)
        if (b >= toff[i] && b < toff[i + 1]) t = i;
    if (t < 0) return;
    int nodeBase = off[t] + (b - toff[t]) * TM;
    int count = min(TM, off[t + 1] - nodeBase);
    int tid = threadIdx.x;

    for (int j = tid; j < TM * 32; j += 256) {
        int row = j >> 5, ch = j & 31;
        ushort4 z = {0, 0, 0, 0};
        if (row < count) {
            int g = order[nodeBase + row];
            const ushort4* p = (const ushort4*)(TBF + (size_t)g * D + ch * 8);
            *(ushort4*)&xs[row][ch * 8] = p[0];
            *(ushort4*)&xs[row][ch * 8 + 4] = p[1];
        } else {
            *(ushort4*)&xs[row][ch * 8] = z;
            *(ushort4*)&xs[row][ch * 8 + 4] = z;
        }
    }
    __syncthreads();

    int lane = tid & 63, wave = tid >> 6;
    int m = lane & 15, quad = lane >> 4;
    v8h a[8];
    #pragma unroll
    for (int ks = 0; ks < 8; ks++)
        a[ks] = *(const v8h*)&xs[wave * 16 + m][ks * 32 + quad * 8];

    int grow[4]; bool vrow[4];
    #pragma unroll
    for (int r = 0; r < 4; r++) {
        int rowi = wave * 16 + quad * 4 + r;
        vrow[r] = (rowi < count);
        grow[r] = vrow[r] ? order[nodeBase + rowi] : 0;
    }

    float sv = skip[t];
    float alpha = 1.f / (1.f + __expf(-sv));
    float beta = 1.f - alpha;
    const u16* W = Wab + (size_t)t * D * D;

    for (int dt = 0; dt < 16; dt++) {
        int dcol = dt * 16 + m;
        v4f acc = {0.f, 0.f, 0.f, 0.f};
        #pragma unroll
        for (int ks = 0; ks < 8; ks++) {
            v8h bf = *(const v8h*)(W + (size_t)dcol * D + ks * 32 + quad * 8);
            acc = __builtin_amdgcn_mfma_f32_16x16x32_f16(a[ks], bf, acc, 0, 0, 0);
        }
        float bias = ba[t * D + dcol];
        #pragma unroll
        for (int r = 0; r < 4; r++) {
            if (vrow[r]) {
                size_t o = (size_t)grow[r] * D + dcol;
                out[o] = alpha * (acc[r] + bias) + beta * x[o];
            }
        }
    }
}

// ---------------- launch ----------------
extern "C" void kernel_launch(void* const* d_in, const int* in_sizes, int n_in,
                              void* d_out, int out_size, void* d_ws, size_t ws_size,
                              hipStream_t stream) {
    const float* x       = (const float*)d_in[0];
    const int* node_type = (const int*)d_in[1];
    const int* src       = (const int*)d_in[2];
    const int* dst       = (const int*)d_in[3];
    const int* etype     = (const int*)d_in[4];
    const float* Wk = (const float*)d_in[5];
    const float* bk = (const float*)d_in[6];
    const float* Wq = (const float*)d_in[7];
    const float* bq = (const float*)d_in[8];
    const float* Wv = (const float*)d_in[9];
    const float* bv = (const float*)d_in[10];
    const float* Wa = (const float*)d_in[11];
    const float* ba = (const float*)d_in[12];
    const float* rel_pri = (const float*)d_in[13];
    const float* rel_att = (const float*)d_in[14];
    const float* rel_msg = (const float*)d_in[15];
    const float* skip    = (const float*)d_in[16];
    float* out = (float*)d_out;
    char* ws = (char*)d_ws;

    // ws (~79.7 MB): Kb | Qb | Vb (f16 node tensors), f16 weights, order,
    // counters. TBF aliases Qb (per-slice read-then-write by same thread).
    const size_t SZH = (size_t)N_NODES * D * 2;          // 25.6 MB
    const size_t WSZ = (size_t)N_T * D * D;              // 262144 elems
    const size_t RSZ = (size_t)N_R * N_H * DKD * DKD;    // 65536 elems
    u16* Kb  = (u16*)(ws);
    u16* Qb  = (u16*)(ws + SZH);
    u16* Vb  = (u16*)(ws + 2 * SZH);
    u16* TBF = Qb;                              // aliases Qb
    u16* Wkb = (u16*)(ws + 3 * SZH);
    u16* Wqb = Wkb + WSZ;
    u16* Wvb = Wqb + WSZ;
    u16* Wab = Wvb + WSZ;
    u16* Ab  = Wab + WSZ;
    u16* Mtb = Ab + RSZ;
    int* order = (int*)(Mtb + RSZ);
    int* small = order + N_NODES;
    int* cnt  = small;        // 4
    int* cur  = small + 4;    // 4
    int* offp = small + 8;    // 5
    int* toffp= small + 13;   // 5

    // d_out as scratch (all dead before k_out rewrites it):
    //   rowptr_seg[S+1] | cnt_seg[S] | cur_seg[S] | esrc[E] | bsum — ~6.4 MB of 51.2 MB
    char* ob = (char*)d_out;
    int* rowptr_seg = (int*)ob;                          // 400001
    int* cnt_seg    = rowptr_seg + (N_SEG + 16);         // 400000
    int* cur_seg    = cnt_seg + N_SEG;                   // 400000 (contiguous w/ cnt)
    int* esrc       = cur_seg + N_SEG;                   // 400000
    int* bsum       = esrc + N_EDGES;                    // 391 (+pad)

    hipMemsetAsync(small, 0, 8 * sizeof(int), stream);
    hipMemsetAsync(cnt_seg, 0, 2 * (size_t)N_SEG * sizeof(int), stream);

    // weight conversions (f32 -> f16)
    k_cvtW<<<(4 * (WSZ / 4) + 255) / 256, 256, 0, stream>>>(
        (const float4*)Wk, (const float4*)Wq, (const float4*)Wv, (const float4*)Wa,
        (ushort4*)Wkb, WSZ / 4);
    k_cvt_att<<<(RSZ / 4 + 255) / 256, 256, 0, stream>>>(
        (const float4*)rel_att, rel_pri, (ushort4*)Ab, RSZ / 4);
    k_cvt_t<<<(RSZ + 255) / 256, 256, 0, stream>>>(rel_msg, Mtb);

    // node-type buckets
    k_hist<<<(N_NODES + 255) / 256, 256, 0, stream>>>(node_type, cnt);
    k_scan<<<1, 1, 0, stream>>>(cnt, offp, toffp);
    k_scatter<<<(N_NODES + 255) / 256, 256, 0, stream>>>(node_type, offp, cur, order);

    // segment CSR (dst*R + etype)
    const int NB = (N_SEG + 1023) / 1024;                // 391
    k_hist_seg<<<(N_EDGES + 255) / 256, 256, 0, stream>>>(dst, etype, cnt_seg);
    k_scan_l1<<<NB, 1024, 0, stream>>>(cnt_seg, rowptr_seg, bsum);
    k_scan_l2<<<1, 512, 0, stream>>>(bsum, NB);
    k_scan_l3<<<(N_SEG + 1 + 255) / 256, 256, 0, stream>>>(rowptr_seg, bsum);
    k_scatter_seg<<<(N_EDGES + 255) / 256, 256, 0, stream>>>(src, dst, etype,
                                                             rowptr_seg, cur_seg, esrc);

    k_proj<<<PROJ_BLOCKS, 256, 0, stream>>>(x, order, offp, toffp,
                                            Wkb, bk, Wqb, bq, Wvb, bv, Kb, Qb, Vb);

    k_fused<<<(N_NODES + 31) / 32, 256, 0, stream>>>(Kb, Qb, Vb, rowptr_seg, esrc,
                                                     Ab, Mtb);

    k_out<<<PROJ_BLOCKS, 256, 0, stream>>>(TBF, x, order, offp, toffp,
                                           Wab, ba, skip, out);
}